// Round 17
// baseline (938.274 us; speedup 1.0000x reference)
//
#include <hip/hip_runtime.h>
#include <math.h>

#define NB 8
#define CIn 32
#define COut 32
#define NIO 1024      // CIn*CO
#define NN1 256
#define NN2 256
#define NYF 129       // NN2/2+1
#define NK1 16
#define NK2 9
#define NKL 144       // NK1*NK2

typedef float2 c32;
typedef __attribute__((ext_vector_type(8))) __bf16 bf16x8;
typedef __attribute__((ext_vector_type(4))) float f32x4;

__device__ __forceinline__ c32 cadd(c32 a, c32 b){ return make_float2(a.x+b.x, a.y+b.y); }
__device__ __forceinline__ c32 csub(c32 a, c32 b){ return make_float2(a.x-b.x, a.y-b.y); }
__device__ __forceinline__ c32 cmul(c32 a, c32 b){ return make_float2(a.x*b.x - a.y*b.y, a.x*b.y + a.y*b.x); }
__device__ __forceinline__ c32 cfma(c32 a, c32 b, c32 acc){
  acc.x = fmaf(a.x, b.x, acc.x); acc.x = fmaf(-a.y, b.y, acc.x);
  acc.y = fmaf(a.x, b.y, acc.y); acc.y = fmaf(a.y, b.x, acc.y);
  return acc;
}
__device__ __forceinline__ unsigned short f2bf(float f){
  unsigned int u = __float_as_uint(f);
  u += 0x7FFF + ((u >> 16) & 1);
  return (unsigned short)(u >> 16);
}
__device__ __forceinline__ float bf2f(unsigned short h){
  unsigned int u = ((unsigned int)h) << 16;
  return __uint_as_float(u);
}
__device__ __forceinline__ void split_bf(float f, unsigned short& hi, unsigned short& lo){
  hi = f2bf(f);
  lo = f2bf(f - bf2f(hi));
}
// hardware v_rcp_f32 (~1ulp) instead of IEEE div sequence (~10 inst)
__device__ __forceinline__ float frcp(float x){ return __builtin_amdgcn_rcpf(x); }

#define GLOAD16(lptr, gptr) \
  __builtin_amdgcn_global_load_lds((const __attribute__((address_space(1))) unsigned int*)(gptr), \
                                   (__attribute__((address_space(3))) unsigned int*)(lptr), 16, 0, 0)

// ---------------- FFT-256 via four-step radix-16 ----------------
template<int INV> __device__ __forceinline__ c32 rot90(c32 a){
  return INV ? make_float2(-a.y, a.x) : make_float2(a.y, -a.x);
}
template<int INV> __device__ __forceinline__ void dft4(c32& a0, c32& a1, c32& a2, c32& a3){
  c32 t0 = cadd(a0,a2), t1 = csub(a0,a2);
  c32 t2 = cadd(a1,a3), t3 = rot90<INV>(csub(a1,a3));
  a0 = cadd(t0,t2); a1 = cadd(t1,t3); a2 = csub(t0,t2); a3 = csub(t1,t3);
}
__device__ __forceinline__ int SLOT16(int k){ return 4*(k&3) + (k>>2); }
template<int INV> __device__ __forceinline__ c32 twg(const float2* ltw, int idx){
  float2 w = ltw[idx & 255];
  return INV ? make_float2(w.x, w.y) : make_float2(w.x, -w.y);
}
template<int INV> __device__ __forceinline__ void fft16r(c32 v[16], const float2* ltw){
#pragma unroll
  for (int bp = 0; bp < 4; bp++) dft4<INV>(v[bp], v[4+bp], v[8+bp], v[12+bp]);
#pragma unroll
  for (int c = 1; c < 4; c++)
#pragma unroll
    for (int bp = 1; bp < 4; bp++)
      v[4*c+bp] = cmul(v[4*c+bp], twg<INV>(ltw, 16*bp*c));
#pragma unroll
  for (int c = 0; c < 4; c++) dft4<INV>(v[4*c], v[4*c+1], v[4*c+2], v[4*c+3]);
}
template<int INV>
__device__ __forceinline__ void fft256_core(c32 v[16], int b, c32* tile, const float2* ltw){
  fft16r<INV>(v, ltw);
#pragma unroll
  for (int c = 0; c < 16; c++){
    c32 g = (c && b) ? cmul(v[SLOT16(c)], twg<INV>(ltw, b*c)) : v[SLOT16(c)];
    tile[c*17 + b] = g;
  }
  __syncthreads();
#pragma unroll
  for (int j = 0; j < 16; j++) v[j] = tile[b*17 + j];
  fft16r<INV>(v, ltw);
}

// ---------- precompute tables ----------
__global__ void k_tw(float2* __restrict__ tw){
  int m = threadIdx.x;
  double ang = 6.283185307179586 * (double)m / 256.0;
  tw[m] = make_float2((float)cos(ang), (float)sin(ang));
}

// P2 layout: [io][y][10 c32 slots], l in 0..8 (slot 9 pad) -> 80B rows
__global__ void k_p2(const float* __restrict__ p2r, const float* __restrict__ p2i, c32* __restrict__ P2){
  int idx = blockIdx.x * 256 + threadIdx.x;   // io*NYF + y
  if (idx >= NIO * NYF) return;
  int io = idx / NYF, y = idx - io * NYF;
  c32* row = P2 + (size_t)idx * 10;
#pragma unroll
  for (int l = 0; l < 9; l++){
    float a = -p2r[io*9 + l];
    float b = 6.2831853071795864f * (float)y - p2i[io*9 + l];
    float inv = frcp(fmaf(a, a, b * b));
    row[l] = make_float2(a * inv, -b * inv);
  }
}

__global__ void k_e1(const float* __restrict__ p1r, const float* __restrict__ p1i, c32* __restrict__ E1){
  int idx = blockIdx.x * 256 + threadIdx.x;
  int z = idx & 255; int iok = idx >> 8;
  float t = (float)z * (1.0f / 256.0f);
  float er = expf(p1r[iok] * t);
  float s, c; sincosf(p1i[iok] * t, &s, &c);
  E1[idx] = make_float2(er * c, er * s);
}

// ---------- forward: rfft along n2 (paired rows), write alpha[(bi*129+y)*256+n1], scaled 1/65536 ----------
__global__ __launch_bounds__(256) void k_fwd_y(const float* __restrict__ x, const float2* __restrict__ tw,
                                               c32* __restrict__ alpha){
  __shared__ c32 tile[16*272];
  __shared__ float2 ltw[256];
  int t = threadIdx.x;
  ltw[t] = tw[t];
  int bi = blockIdx.x >> 3;
  int n1c = (blockIdx.x & 7) << 5;
  int row = t >> 4, b = t & 15;
  const float* xe = x + ((size_t)bi * 256 + n1c + 2 * row) * 256;
  c32 v[16];
#pragma unroll
  for (int a = 0; a < 16; a++)
    v[a] = make_float2(xe[16*a + b], xe[256 + 16*a + b]);
  __syncthreads();
  fft256_core<0>(v, b, tile + row*272, ltw);
  __syncthreads();
#pragma unroll
  for (int d = 0; d < 16; d++)
    tile[row*272 + b + 16*d] = v[SLOT16(d)];
  __syncthreads();
  const float sc = 0.5f / 65536.0f;
#pragma unroll
  for (int j = 0; j < 8; j++){
    int item = t + 256*j;
    int h = item & 127, r2 = item >> 7;
    c32* Zb = tile + r2*272;
    if (h == 0){
      c32 z0 = Zb[0], z1 = Zb[128];
      Zb[0]   = make_float2(z0.x * (2.0f*sc), z0.y * (2.0f*sc));
      Zb[128] = make_float2(z1.x * (2.0f*sc), z1.y * (2.0f*sc));
    } else {
      c32 zk = Zb[h], zm = Zb[256 - h];
      c32 A = make_float2(sc*(zk.x + zm.x), sc*(zk.y - zm.y));
      c32 B = make_float2(sc*(zk.y + zm.y), sc*(zm.x - zk.x));
      Zb[h] = A; Zb[256 - h] = B;
    }
  }
  __syncthreads();
  for (int j = 0; j < 17; j++){
    int idx = t + 256*j;
    if (idx >= 129*32) break;
    int y = idx >> 5, n1i = idx & 31;
    c32* Zb = tile + (n1i >> 1)*272;
    c32 val;
    if ((n1i & 1) == 0)
      val = (y == 0) ? make_float2(Zb[0].x, 0.0f)
          : (y == 128) ? make_float2(Zb[128].x, 0.0f) : Zb[y];
    else
      val = (y == 0) ? make_float2(Zb[0].y, 0.0f)
          : (y == 128) ? make_float2(Zb[128].y, 0.0f) : Zb[256 - y];
    alpha[((size_t)bi * 129 + y) * 256 + n1c + n1i] = val;
  }
}

// ---------- complex FFT-256 on contiguous rows, in place ----------
template<int INV>
__global__ __launch_bounds__(256) void k_fft_x(const float2* __restrict__ tw, c32* __restrict__ buf){
  __shared__ c32 tile[16*272];
  __shared__ float2 ltw[256];
  int t = threadIdx.x;
  ltw[t] = tw[t];
  int row = t >> 4, b = t & 15;
  c32* p = buf + ((size_t)blockIdx.x * 16 + row) * 256;
  c32 v[16];
#pragma unroll
  for (int a = 0; a < 16; a++) v[a] = p[16*a + b];
  __syncthreads();
  fft256_core<INV>(v, b, tile + row*272, ltw);
#pragma unroll
  for (int d = 0; d < 16; d++) p[b + 16*d] = v[SLOT16(d)];
}

// ---------- inverse rfft along y (paired z-columns) + bias, writes out ----------
__global__ __launch_bounds__(256) void k_inv_y(const c32* __restrict__ r1, const float* __restrict__ bias,
                                               const float2* __restrict__ tw, float* __restrict__ out){
  __shared__ c32 tile[16*272];
  __shared__ float2 ltw[256];
  c32* SA = tile;
  int t = threadIdx.x;
  ltw[t] = tw[t];
  int bo = blockIdx.x >> 3;
  int z0 = (blockIdx.x & 7) << 5;
  for (int j = 0; j < 17; j++){
    int idx = t + 256*j;
    if (idx >= 129*32) break;
    int y = idx >> 5, zi = idx & 31;
    SA[y*33 + zi] = r1[((size_t)bo * 129 + y) * 256 + z0 + zi];
  }
  __syncthreads();
  int p = t >> 4, b = t & 15;
  c32 v[16];
#pragma unroll
  for (int a = 0; a < 16; a++){
    int k = 16*a + b;
    int m = (k <= 128) ? k : 256 - k;
    c32 A = SA[m*33 + 2*p], B = SA[m*33 + 2*p + 1];
    if (k == 0 || k == 128)  v[a] = make_float2(A.x, B.x);
    else if (k < 128)        v[a] = make_float2(A.x - B.y, A.y + B.x);
    else                     v[a] = make_float2(A.x + B.y, B.x - A.y);
  }
  __syncthreads();
  fft256_core<1>(v, b, tile + p*272, ltw);
  float bv = bias[bo & 31];
  float* o0 = out + ((size_t)bo * 256 + z0 + 2*p) * 256;
#pragma unroll
  for (int d = 0; d < 16; d++){
    c32 zz = v[SLOT16(d)];
    o0[b + 16*d]       = zz.x + bv;
    o0[256 + b + 16*d] = zz.y + bv;
  }
}

// ---------- mode mixing r1: y4-tile, x-pair float4 loads, y-half-split R2 in LDS ----------
// 256 threads = 128 x-pairs * 2 y-halves. grid 1056 = 8 XCD chunks * 132 (y-major).
__global__ __launch_bounds__(256, 4) void k_r1(const c32* __restrict__ alpha,
                                               const float* __restrict__ rr, const float* __restrict__ ri,
                                               const float* __restrict__ p1r, const float* __restrict__ p1i,
                                               const c32* __restrict__ P2,
                                               c32* __restrict__ r1){
  __shared__ float4 R2h[2][512];   // [yhalf][i*16+k] = (r@yA, r@yB, i@yA, i@yB), 16KB
  int t = threadIdx.x;
  int j = blockIdx.x;
  int g = (j & 7) * 132 + (j >> 3);          // XCD-chunked
  int y4 = g >> 5, o = g & 31;               // y4: 0..32
  int y0 = y4 * 4;
  // build R2 for 4 y's, pre-split by y-half
#pragma unroll
  for (int e = 0; e < 2; e++){
    int flat = t + e * 256;                  // i*16 + k
    int i = flat >> 4, k = flat & 15;
    int io = i * 32 + o;
    int iok = io * 16 + k;
    float ar[4] = {0.f,0.f,0.f,0.f}, ai[4] = {0.f,0.f,0.f,0.f};
#pragma unroll
    for (int l = 0; l < 9; l++){
      float rsr = rr[iok*9 + l], rsi = ri[iok*9 + l];
#pragma unroll
      for (int yy = 0; yy < 4; yy++){
        int ya = y0 + yy; if (ya > 128) ya = 128;
        c32 p2 = P2[((size_t)io * NYF + ya) * 10 + l];
        ar[yy] = fmaf(rsr, p2.x, ar[yy]); ar[yy] = fmaf(-rsi, p2.y, ar[yy]);
        ai[yy] = fmaf(rsr, p2.y, ai[yy]); ai[yy] = fmaf( rsi, p2.x, ai[yy]);
      }
    }
    R2h[0][flat] = make_float4(ar[0], ar[1], ai[0], ai[1]);
    R2h[1][flat] = make_float4(ar[2], ar[3], ai[2], ai[3]);
  }
  __syncthreads();
  int xp = t & 127, yh = t >> 7;
  int x0 = 2 * xp;
  int yA = y0 + 2 * yh;                      // thread's y pair: yA, yA+1
  int yAc = (yA     > 128) ? 128 : yA;
  int yBc = (yA + 1 > 128) ? 128 : yA + 1;
  bool wA = (yA     <= 128);
  bool wB = (yA + 1 <= 128);
  float fx0 = (x0     < 128) ? (float)x0       : (float)(x0 - 256);
  float fx1 = (x0 + 1 < 128) ? (float)(x0 + 1) : (float)(x0 + 1 - 256);
  float lam0 = 6.2831853071795864f * fx0;
  float lam1 = 6.2831853071795864f * fx1;
  const float4* __restrict__ R2u = R2h[yh];  // wave-uniform base
  float acr[8][2][2], aci[8][2][2];          // [b][y 0/1][x 0/1]
#pragma unroll
  for (int b = 0; b < 8; b++)
#pragma unroll
    for (int yy = 0; yy < 2; yy++){
      acr[b][yy][0] = 0.f; acr[b][yy][1] = 0.f;
      aci[b][yy][0] = 0.f; aci[b][yy][1] = 0.f;
    }
  size_t yoffA = (size_t)yAc * 256, yoffB = (size_t)yBc * 256;
  for (int i = 0; i < 32; i++){
    int io = i * 32 + o;
    const float* pr = p1r + io * 16;
    const float* pim = p1i + io * 16;
    float hwr[2][2] = {{0.f,0.f},{0.f,0.f}};  // [y][x]
    float hwi[2][2] = {{0.f,0.f},{0.f,0.f}};
#pragma unroll
    for (int k = 0; k < 16; k++){
      float a = -pr[k];
      float b0 = lam0 - pim[k];
      float b1 = lam1 - pim[k];
      float inv0 = frcp(fmaf(a, a, b0 * b0));
      float inv1 = frcp(fmaf(a, a, b1 * b1));
      float px0 = a * inv0, py0 = -b0 * inv0;
      float px1 = a * inv1, py1 = -b1 * inv1;
      float4 q = R2u[i*16 + k];               // (rA, rB, iA, iB)
      hwr[0][0] = fmaf(px0, q.x, hwr[0][0]); hwr[0][0] = fmaf(-py0, q.z, hwr[0][0]);
      hwi[0][0] = fmaf(px0, q.z, hwi[0][0]); hwi[0][0] = fmaf( py0, q.x, hwi[0][0]);
      hwr[0][1] = fmaf(px1, q.x, hwr[0][1]); hwr[0][1] = fmaf(-py1, q.z, hwr[0][1]);
      hwi[0][1] = fmaf(px1, q.z, hwi[0][1]); hwi[0][1] = fmaf( py1, q.x, hwi[0][1]);
      hwr[1][0] = fmaf(px0, q.y, hwr[1][0]); hwr[1][0] = fmaf(-py0, q.w, hwr[1][0]);
      hwi[1][0] = fmaf(px0, q.w, hwi[1][0]); hwi[1][0] = fmaf( py0, q.y, hwi[1][0]);
      hwr[1][1] = fmaf(px1, q.y, hwr[1][1]); hwr[1][1] = fmaf(-py1, q.w, hwr[1][1]);
      hwi[1][1] = fmaf(px1, q.w, hwi[1][1]); hwi[1][1] = fmaf( py1, q.y, hwi[1][1]);
    }
    const c32* ab = alpha + (size_t)i * 129 * 256 + x0;
#pragma unroll
    for (int b = 0; b < 8; b++){
      const c32* ap = ab + (size_t)b * 32 * 129 * 256;
      float4 vA = *(const float4*)(ap + yoffA);   // (re@x0, im@x0, re@x1, im@x1)
      float4 vB = *(const float4*)(ap + yoffB);
      acr[b][0][0]=fmaf(vA.x,hwr[0][0],acr[b][0][0]); acr[b][0][0]=fmaf(-vA.y,hwi[0][0],acr[b][0][0]);
      aci[b][0][0]=fmaf(vA.x,hwi[0][0],aci[b][0][0]); aci[b][0][0]=fmaf( vA.y,hwr[0][0],aci[b][0][0]);
      acr[b][0][1]=fmaf(vA.z,hwr[0][1],acr[b][0][1]); acr[b][0][1]=fmaf(-vA.w,hwi[0][1],acr[b][0][1]);
      aci[b][0][1]=fmaf(vA.z,hwi[0][1],aci[b][0][1]); aci[b][0][1]=fmaf( vA.w,hwr[0][1],aci[b][0][1]);
      acr[b][1][0]=fmaf(vB.x,hwr[1][0],acr[b][1][0]); acr[b][1][0]=fmaf(-vB.y,hwi[1][0],acr[b][1][0]);
      aci[b][1][0]=fmaf(vB.x,hwi[1][0],aci[b][1][0]); aci[b][1][0]=fmaf( vB.y,hwr[1][0],aci[b][1][0]);
      acr[b][1][1]=fmaf(vB.z,hwr[1][1],acr[b][1][1]); acr[b][1][1]=fmaf(-vB.w,hwi[1][1],acr[b][1][1]);
      aci[b][1][1]=fmaf(vB.z,hwi[1][1],aci[b][1][1]); aci[b][1][1]=fmaf( vB.w,hwr[1][1],aci[b][1][1]);
    }
  }
#pragma unroll
  for (int b = 0; b < 8; b++){
    if (wA){
      float4 st = make_float4(acr[b][0][0], aci[b][0][0], acr[b][0][1], aci[b][0][1]);
      *(float4*)(r1 + (((size_t)(b*32 + o) * 129) + yA) * 256 + x0) = st;
    }
    if (wB){
      float4 st = make_float4(acr[b][1][0], aci[b][1][0], acr[b][1][1], aci[b][1][1]);
      *(float4*)(r1 + (((size_t)(b*32 + o) * 129) + yA + 1) * 256 + x0) = st;
    }
  }
}

// ---------- r2[b,io,k,l]: o-PAIR per block. phase1 dual-accum (72 FMA / alpha load), ----------
// ---------- phase2 runs twice reusing the 22528B stride-11 Ts buffer ----------
__global__ __launch_bounds__(256) void k_r2k(const c32* __restrict__ alpha,
                                             const float* __restrict__ p1r, const float* __restrict__ p1i,
                                             const c32* __restrict__ P2,
                                             const float* __restrict__ rr, const float* __restrict__ ri,
                                             c32* __restrict__ r2){
  __shared__ c32 Ts[256 * 11];
  int t = threadIdx.x;
  int j = blockIdx.x;               // 4096 = 8 XCD * 512
  int bid = (j & 7) * 512 + (j >> 3);   // same-bi (16 o-pairs) consecutive per XCD
  int op = bid & 15; int bi = bid >> 4;
  int i = bi & 31;  int b = bi >> 5;
  int io0 = i * COut + op * 2;
  int io1 = io0 + 1;
  float tr0[9], ti0[9], tr1[9], ti1[9];
  { // phase 1: dual-o accumulation; P2 rows wave-uniform -> SMEM pipe
#pragma unroll
    for (int l = 0; l < 9; l++){ tr0[l]=0.f; ti0[l]=0.f; tr1[l]=0.f; ti1[l]=0.f; }
    const c32* ap = alpha + (size_t)bi * NYF * 256 + t;
    const float* __restrict__ P2u0 = (const float*)(P2 + (size_t)io0 * NYF * 10);
    const float* __restrict__ P2u1 = (const float*)(P2 + (size_t)io1 * NYF * 10);
    c32 a0 = ap[0], a1 = ap[256], a2 = ap[512], a3 = ap[768];
#define R2K_BODY(aa, Y, PF) { \
      const float* prw0 = P2u0 + (size_t)(Y) * 20; \
      const float* prw1 = P2u1 + (size_t)(Y) * 20; \
      float axr = (aa).x, ayi = (aa).y; \
      PF; \
      _Pragma("unroll") \
      for (int l = 0; l < 9; l++){ \
        float pc0 = prw0[2*l], ps0 = prw0[2*l+1]; \
        float pc1 = prw1[2*l], ps1 = prw1[2*l+1]; \
        tr0[l] = fmaf(axr, pc0, tr0[l]); tr0[l] = fmaf(-ayi, ps0, tr0[l]); \
        ti0[l] = fmaf(axr, ps0, ti0[l]); ti0[l] = fmaf( ayi, pc0, ti0[l]); \
        tr1[l] = fmaf(axr, pc1, tr1[l]); tr1[l] = fmaf(-ayi, ps1, tr1[l]); \
        ti1[l] = fmaf(axr, ps1, ti1[l]); ti1[l] = fmaf( ayi, pc1, ti1[l]); } }
    for (int yb = 0; yb < 128; yb += 4){
      R2K_BODY(a0, yb+0, a0 = ap[(size_t)(yb+4)*256]);
      R2K_BODY(a1, yb+1, a1 = ap[(size_t)(yb+5)*256]);
      R2K_BODY(a2, yb+2, a2 = ap[(size_t)(yb+6)*256]);
      R2K_BODY(a3, yb+3, a3 = ap[(size_t)(yb+7)*256]);
    }
    R2K_BODY(a0, 128, );
#undef R2K_BODY
  }
  // phase 2 macro: consumes Ts (written just before call) for pole set IO
#define R2K_PHASE2(IO) { \
    int k = t >> 4, c = t & 15; \
    float pa = -p1r[(IO)*16 + k]; \
    float pb =  p1i[(IO)*16 + k]; \
    float gr[9], gi[9]; \
    _Pragma("unroll") \
    for (int l = 0; l < 9; l++){ gr[l] = 0.f; gi[l] = 0.f; } \
    _Pragma("unroll 4") \
    for (int jj = 0; jj < 16; jj++){ \
      int xx = c + 16*jj; \
      float fx = (xx < 128) ? (float)xx : (float)(xx - 256); \
      float bb = 6.2831853071795864f * fx - pb; \
      float inv = frcp(fmaf(pa, pa, bb * bb)); \
      float px = pa * inv, py = -bb * inv; \
      const c32* trow = Ts + xx * 11; \
      _Pragma("unroll") \
      for (int l = 0; l < 9; l++){ \
        c32 q = trow[l]; \
        gr[l] = fmaf(px, q.x, gr[l]); gr[l] = fmaf(-py, q.y, gr[l]); \
        gi[l] = fmaf(px, q.y, gi[l]); gi[l] = fmaf( py, q.x, gi[l]); } } \
    _Pragma("unroll") \
    for (int s = 1; s < 16; s <<= 1){ \
      _Pragma("unroll") \
      for (int l = 0; l < 9; l++){ \
        gr[l] += __shfl_xor(gr[l], s, 64); \
        gi[l] += __shfl_xor(gi[l], s, 64); } } \
    if (c == 0){ \
      _Pragma("unroll") \
      for (int l = 0; l < 9; l++){ \
        float resr = rr[((IO)*16 + k)*9 + l]; \
        float resi = ri[((IO)*16 + k)*9 + l]; \
        r2[((size_t)b * NIO + (IO)) * NKL + k*9 + l] = \
          make_float2(-(resr*gr[l] - resi*gi[l]), -(resr*gi[l] + resi*gr[l])); } } }
  {
    c32* myrow = Ts + t * 11;
#pragma unroll
    for (int l = 0; l < 9; l++) myrow[l] = make_float2(tr0[l], ti0[l]);
  }
  __syncthreads();
  R2K_PHASE2(io0);
  __syncthreads();
  {
    c32* myrow = Ts + t * 11;
#pragma unroll
    for (int l = 0; l < 9; l++) myrow[l] = make_float2(tr1[l], ti1[l]);
  }
  __syncthreads();
  R2K_PHASE2(io1);
#undef R2K_PHASE2
}

// ---------- x2 path: split-bf16 MFMA GEMM pipeline ----------
__global__ __launch_bounds__(256) void k_e2b(const float* __restrict__ p2r, const float* __restrict__ p2i,
                                             unsigned int* __restrict__ B){
  int j = blockIdx.x;
  int o = j & 31, ic = j >> 5;
  int w = threadIdx.x;
  float tt = (float)w * (1.0f / 256.0f);
  unsigned int* brow = B + ((size_t)o * 256 + w) * 576;   // 576 uints = 1152 halves
#pragma unroll
  for (int ii = 0; ii < 4; ii++){
    int i = ic * 4 + ii;
    int io = i * 32 + o;
#pragma unroll
    for (int l = 0; l < 9; l++){
      float pr = p2r[io*9 + l], pi = p2i[io*9 + l];
      float er = expf(pr * tt);
      float s, c; sincosf(pi * tt, &s, &c);
      float vr = er * c, vi = -er * s;
      unsigned short rh, rl, ih, il;
      split_bf(vr, rh, rl); split_bf(vi, ih, il);
      brow[i*9 + l]       = (unsigned int)rh | ((unsigned int)ih << 16);
      brow[288 + i*9 + l] = (unsigned int)rl | ((unsigned int)il << 16);
    }
  }
}

__global__ __launch_bounds__(256) void k_v(const c32* __restrict__ r2, const c32* __restrict__ E1,
                                           unsigned int* __restrict__ Ahi, unsigned int* __restrict__ Alo){
  int t = threadIdx.x;                 // z
  int j = blockIdx.x;                  // 1024
  int o = j & 31;
  int rest = j >> 5;                   // 0..31
  int b = rest & 7, ic = rest >> 3;    // ic 0..3
  size_t rowoff = ((size_t)o * 2048 + b * 256 + t) * 288;
  unsigned int* AH = Ahi + rowoff;
  unsigned int* AL = Alo + rowoff;
#pragma unroll 1
  for (int ii = 0; ii < 8; ii++){
    int i = ic * 8 + ii;
    int io = i * 32 + o;
    const c32* e1p = E1 + (size_t)io * 16 * 256 + t;
    c32 e[16];
#pragma unroll
    for (int k = 0; k < 16; k++) e[k] = e1p[(size_t)k * 256];
    const c32* rp = r2 + ((size_t)b * NIO + io) * NKL;
#pragma unroll
    for (int l = 0; l < 9; l++){
      c32 acc = make_float2(0.0f, 0.0f);
#pragma unroll
      for (int k = 0; k < 16; k++) acc = cfma(rp[k*9 + l], e[k], acc);
      unsigned short rh, rl, ih, il;
      split_bf(acc.x, rh, rl); split_bf(acc.y, ih, il);
      AH[i*9 + l] = (unsigned int)rh | ((unsigned int)ih << 16);
      AL[i*9 + l] = (unsigned int)rl | ((unsigned int)il << 16);
    }
  }
}

// GEMM: per o: C[2048][256] += Re(A*B^T), split-bf16 3-product schedule, 54 K-chunks of 32.
#define ALO_H 37748736u
__global__ __launch_bounds__(256) void k_x2m(const unsigned short* __restrict__ A,
                                             const unsigned short* __restrict__ B,
                                             float* __restrict__ out){
  __shared__ __align__(16) unsigned short At[128*32];
  __shared__ __align__(16) unsigned short Bt[128*32];
  int t = threadIdx.x;
  int j = blockIdx.x;                   // 1024
  int orig = (j & 7) * 128 + (j >> 3);  // same-o blocks grouped per XCD
  int o  = orig >> 5;
  int mb = (orig >> 1) & 15;
  int nb = orig & 1;
  const unsigned short* Ab = A + ((size_t)o*2048 + mb*128 + (t>>2))*576 + (t&3)*8;
  const unsigned short* Bb = B + ((size_t)o*256  + nb*128 + (t>>2))*1152 + (t&3)*8;
  int ln = t & 63;
  int wm = t >> 7, wn = (t >> 6) & 1;
  int lrow = ln & 15, lk = (ln >> 4) * 8;
  f32x4 acc[4][4];
#pragma unroll
  for (int mi = 0; mi < 4; mi++)
#pragma unroll
    for (int ni = 0; ni < 4; ni++) acc[mi][ni] = (f32x4){0.f,0.f,0.f,0.f};

  for (int ks = 0; ks < 54; ks++){
    int kA = ks % 18;
    int kB = ks % 36;
    const unsigned short* Ap = Ab + (ks >= 36 ? (size_t)ALO_H : 0) + (size_t)kA*32;
    __syncthreads();
    GLOAD16(At + (size_t)t*8,        Ap);
    GLOAD16(At + 2048 + (size_t)t*8, Ap + (size_t)64*576);
    GLOAD16(Bt + (size_t)t*8,        Bb + (size_t)kB*32);
    GLOAD16(Bt + 2048 + (size_t)t*8, Bb + (size_t)kB*32 + (size_t)64*1152);
    __syncthreads();
    bf16x8 av[4], bv[4];
#pragma unroll
    for (int mi = 0; mi < 4; mi++)
      av[mi] = *(const bf16x8*)(At + (wm*64 + mi*16 + lrow)*32 + lk);
#pragma unroll
    for (int ni = 0; ni < 4; ni++)
      bv[ni] = *(const bf16x8*)(Bt + (wn*64 + ni*16 + lrow)*32 + lk);
#pragma unroll
    for (int mi = 0; mi < 4; mi++)
#pragma unroll
      for (int ni = 0; ni < 4; ni++)
        acc[mi][ni] = __builtin_amdgcn_mfma_f32_16x16x32_bf16(av[mi], bv[ni], acc[mi][ni], 0, 0, 0);
  }
  int nglob = nb*128 + wn*64 + (ln & 15);
#pragma unroll
  for (int mi = 0; mi < 4; mi++){
#pragma unroll
    for (int r = 0; r < 4; r++){
      int m = mb*128 + wm*64 + mi*16 + (ln >> 4)*4 + r;
      int b = m >> 8, z = m & 255;
      float* op = out + (((size_t)(b*32 + o) * 256 + z) * 256) + nglob;
#pragma unroll
      for (int ni = 0; ni < 4; ni++)
        op[ni*16] += acc[mi][ni][r];
    }
  }
}

extern "C" void kernel_launch(void* const* d_in, const int* in_sizes, int n_in,
                              void* d_out, int out_size, void* d_ws, size_t ws_size,
                              hipStream_t stream){
  const float* x    = (const float*)d_in[0];
  const float* rr   = (const float*)d_in[1];
  const float* ri   = (const float*)d_in[2];
  const float* p1r  = (const float*)d_in[3];
  const float* p1i  = (const float*)d_in[4];
  const float* p2r  = (const float*)d_in[5];
  const float* p2i  = (const float*)d_in[6];
  const float* bias = (const float*)d_in[7];
  float* out = (float*)d_out;

  // ws layout (offsets unchanged; P2b in old R2b hole)
  char* ws = (char*)d_ws;
  size_t off = 0;
  c32* alpha = (c32*)(ws + off); off += (size_t)NB * CIn * NYF * NN1 * sizeof(c32);   // 67.6 MB
  c32* r1b   = (c32*)(ws + off); off += (size_t)NB * COut * NYF * NN1 * sizeof(c32);  // 67.6 MB
  off += (size_t)NIO * NK1 * NN1 * sizeof(c32);                                       // (hole)
  c32* P2b   = (c32*)(ws + off); off += (size_t)NIO * NYF * 10 * sizeof(c32);         // 10.6 MB
  off += (size_t)NIO * NK1 * NYF * sizeof(c32) - (size_t)NIO * NYF * 10 * sizeof(c32)
       + (size_t)NIO * NK2 * NYF * sizeof(c32);                                       // keep E1b offset identical
  c32* E1b   = (c32*)(ws + off); off += (size_t)NIO * NK1 * NN1 * sizeof(c32);        // 33.6 MB
  c32* r2b   = (c32*)(ws + off); off += (size_t)NB * NIO * NKL * sizeof(c32);         //  9.4 MB
  float2* tw = (float2*)(ws + off); off += 256 * sizeof(float2);
  unsigned short* Abf  = (unsigned short*)(ws + 0);
  unsigned short* E2bf = (unsigned short*)(ws + 150994944);

  k_tw<<<1, 256, 0, stream>>>(tw);
  k_p2<<<(NIO * NYF + 255) / 256, 256, 0, stream>>>(p2r, p2i, P2b);
  k_e1<<<NIO * NK1, 256, 0, stream>>>(p1r, p1i, E1b);

  k_fwd_y<<<NB * CIn * 8, 256, 0, stream>>>(x, tw, alpha);
  k_fft_x<0><<<NB * CIn * NYF / 16, 256, 0, stream>>>(tw, alpha);

  k_r1<<<1056, 256, 0, stream>>>(alpha, rr, ri, p1r, p1i, P2b, r1b);
  k_r2k<<<NB * CIn * COut / 2, 256, 0, stream>>>(alpha, p1r, p1i, P2b, rr, ri, r2b);

  k_fft_x<1><<<NB * COut * NYF / 16, 256, 0, stream>>>(tw, r1b);
  k_inv_y<<<NB * COut * 8, 256, 0, stream>>>(r1b, bias, tw, out);

  k_e2b<<<256, 256, 0, stream>>>(p2r, p2i, (unsigned int*)E2bf);
  k_v<<<1024, 256, 0, stream>>>(r2b, E1b, (unsigned int*)Abf, (unsigned int*)(Abf + ALO_H));
  k_x2m<<<1024, 256, 0, stream>>>(Abf, E2bf, out);
}

// Round 18
// 919.703 us; speedup vs baseline: 1.0202x; 1.0202x over previous
//
#include <hip/hip_runtime.h>
#include <math.h>

#define NB 8
#define CIn 32
#define COut 32
#define NIO 1024      // CIn*CO
#define NN1 256
#define NN2 256
#define NYF 129       // NN2/2+1
#define NK1 16
#define NK2 9
#define NKL 144       // NK1*NK2

typedef float2 c32;
typedef __attribute__((ext_vector_type(8))) __bf16 bf16x8;
typedef __attribute__((ext_vector_type(4))) float f32x4;

__device__ __forceinline__ c32 cadd(c32 a, c32 b){ return make_float2(a.x+b.x, a.y+b.y); }
__device__ __forceinline__ c32 csub(c32 a, c32 b){ return make_float2(a.x-b.x, a.y-b.y); }
__device__ __forceinline__ c32 cmul(c32 a, c32 b){ return make_float2(a.x*b.x - a.y*b.y, a.x*b.y + a.y*b.x); }
__device__ __forceinline__ c32 cfma(c32 a, c32 b, c32 acc){
  acc.x = fmaf(a.x, b.x, acc.x); acc.x = fmaf(-a.y, b.y, acc.x);
  acc.y = fmaf(a.x, b.y, acc.y); acc.y = fmaf(a.y, b.x, acc.y);
  return acc;
}
__device__ __forceinline__ unsigned short f2bf(float f){
  unsigned int u = __float_as_uint(f);
  u += 0x7FFF + ((u >> 16) & 1);
  return (unsigned short)(u >> 16);
}
__device__ __forceinline__ float bf2f(unsigned short h){
  unsigned int u = ((unsigned int)h) << 16;
  return __uint_as_float(u);
}
__device__ __forceinline__ void split_bf(float f, unsigned short& hi, unsigned short& lo){
  hi = f2bf(f);
  lo = f2bf(f - bf2f(hi));
}
// hardware v_rcp_f32 (~1ulp) instead of IEEE div sequence (~10 inst)
__device__ __forceinline__ float frcp(float x){ return __builtin_amdgcn_rcpf(x); }

#define GLOAD16(lptr, gptr) \
  __builtin_amdgcn_global_load_lds((const __attribute__((address_space(1))) unsigned int*)(gptr), \
                                   (__attribute__((address_space(3))) unsigned int*)(lptr), 16, 0, 0)

// ---------------- FFT-256 via four-step radix-16 ----------------
template<int INV> __device__ __forceinline__ c32 rot90(c32 a){
  return INV ? make_float2(-a.y, a.x) : make_float2(a.y, -a.x);
}
template<int INV> __device__ __forceinline__ void dft4(c32& a0, c32& a1, c32& a2, c32& a3){
  c32 t0 = cadd(a0,a2), t1 = csub(a0,a2);
  c32 t2 = cadd(a1,a3), t3 = rot90<INV>(csub(a1,a3));
  a0 = cadd(t0,t2); a1 = cadd(t1,t3); a2 = csub(t0,t2); a3 = csub(t1,t3);
}
__device__ __forceinline__ int SLOT16(int k){ return 4*(k&3) + (k>>2); }
template<int INV> __device__ __forceinline__ c32 twg(const float2* ltw, int idx){
  float2 w = ltw[idx & 255];
  return INV ? make_float2(w.x, w.y) : make_float2(w.x, -w.y);
}
template<int INV> __device__ __forceinline__ void fft16r(c32 v[16], const float2* ltw){
#pragma unroll
  for (int bp = 0; bp < 4; bp++) dft4<INV>(v[bp], v[4+bp], v[8+bp], v[12+bp]);
#pragma unroll
  for (int c = 1; c < 4; c++)
#pragma unroll
    for (int bp = 1; bp < 4; bp++)
      v[4*c+bp] = cmul(v[4*c+bp], twg<INV>(ltw, 16*bp*c));
#pragma unroll
  for (int c = 0; c < 4; c++) dft4<INV>(v[4*c], v[4*c+1], v[4*c+2], v[4*c+3]);
}
template<int INV>
__device__ __forceinline__ void fft256_core(c32 v[16], int b, c32* tile, const float2* ltw){
  fft16r<INV>(v, ltw);
#pragma unroll
  for (int c = 0; c < 16; c++){
    c32 g = (c && b) ? cmul(v[SLOT16(c)], twg<INV>(ltw, b*c)) : v[SLOT16(c)];
    tile[c*17 + b] = g;
  }
  __syncthreads();
#pragma unroll
  for (int j = 0; j < 16; j++) v[j] = tile[b*17 + j];
  fft16r<INV>(v, ltw);
}

// ---------- precompute tables ----------
__global__ void k_tw(float2* __restrict__ tw){
  int m = threadIdx.x;
  double ang = 6.283185307179586 * (double)m / 256.0;
  tw[m] = make_float2((float)cos(ang), (float)sin(ang));
}

// P2 layout: [io][y][10 c32 slots], l in 0..8 (slot 9 pad) -> 80B rows
__global__ void k_p2(const float* __restrict__ p2r, const float* __restrict__ p2i, c32* __restrict__ P2){
  int idx = blockIdx.x * 256 + threadIdx.x;   // io*NYF + y
  if (idx >= NIO * NYF) return;
  int io = idx / NYF, y = idx - io * NYF;
  c32* row = P2 + (size_t)idx * 10;
#pragma unroll
  for (int l = 0; l < 9; l++){
    float a = -p2r[io*9 + l];
    float b = 6.2831853071795864f * (float)y - p2i[io*9 + l];
    float inv = frcp(fmaf(a, a, b * b));
    row[l] = make_float2(a * inv, -b * inv);
  }
}

__global__ void k_e1(const float* __restrict__ p1r, const float* __restrict__ p1i, c32* __restrict__ E1){
  int idx = blockIdx.x * 256 + threadIdx.x;
  int z = idx & 255; int iok = idx >> 8;
  float t = (float)z * (1.0f / 256.0f);
  float er = expf(p1r[iok] * t);
  float s, c; sincosf(p1i[iok] * t, &s, &c);
  E1[idx] = make_float2(er * c, er * s);
}

// ---------- forward: rfft along n2 (paired rows), write alpha[(bi*129+y)*256+n1], scaled 1/65536 ----------
__global__ __launch_bounds__(256) void k_fwd_y(const float* __restrict__ x, const float2* __restrict__ tw,
                                               c32* __restrict__ alpha){
  __shared__ c32 tile[16*272];
  __shared__ float2 ltw[256];
  int t = threadIdx.x;
  ltw[t] = tw[t];
  int bi = blockIdx.x >> 3;
  int n1c = (blockIdx.x & 7) << 5;
  int row = t >> 4, b = t & 15;
  const float* xe = x + ((size_t)bi * 256 + n1c + 2 * row) * 256;
  c32 v[16];
#pragma unroll
  for (int a = 0; a < 16; a++)
    v[a] = make_float2(xe[16*a + b], xe[256 + 16*a + b]);
  __syncthreads();
  fft256_core<0>(v, b, tile + row*272, ltw);
  __syncthreads();
#pragma unroll
  for (int d = 0; d < 16; d++)
    tile[row*272 + b + 16*d] = v[SLOT16(d)];
  __syncthreads();
  const float sc = 0.5f / 65536.0f;
#pragma unroll
  for (int j = 0; j < 8; j++){
    int item = t + 256*j;
    int h = item & 127, r2 = item >> 7;
    c32* Zb = tile + r2*272;
    if (h == 0){
      c32 z0 = Zb[0], z1 = Zb[128];
      Zb[0]   = make_float2(z0.x * (2.0f*sc), z0.y * (2.0f*sc));
      Zb[128] = make_float2(z1.x * (2.0f*sc), z1.y * (2.0f*sc));
    } else {
      c32 zk = Zb[h], zm = Zb[256 - h];
      c32 A = make_float2(sc*(zk.x + zm.x), sc*(zk.y - zm.y));
      c32 B = make_float2(sc*(zk.y + zm.y), sc*(zm.x - zk.x));
      Zb[h] = A; Zb[256 - h] = B;
    }
  }
  __syncthreads();
  for (int j = 0; j < 17; j++){
    int idx = t + 256*j;
    if (idx >= 129*32) break;
    int y = idx >> 5, n1i = idx & 31;
    c32* Zb = tile + (n1i >> 1)*272;
    c32 val;
    if ((n1i & 1) == 0)
      val = (y == 0) ? make_float2(Zb[0].x, 0.0f)
          : (y == 128) ? make_float2(Zb[128].x, 0.0f) : Zb[y];
    else
      val = (y == 0) ? make_float2(Zb[0].y, 0.0f)
          : (y == 128) ? make_float2(Zb[128].y, 0.0f) : Zb[256 - y];
    alpha[((size_t)bi * 129 + y) * 256 + n1c + n1i] = val;
  }
}

// ---------- complex FFT-256 on contiguous rows, in place ----------
template<int INV>
__global__ __launch_bounds__(256) void k_fft_x(const float2* __restrict__ tw, c32* __restrict__ buf){
  __shared__ c32 tile[16*272];
  __shared__ float2 ltw[256];
  int t = threadIdx.x;
  ltw[t] = tw[t];
  int row = t >> 4, b = t & 15;
  c32* p = buf + ((size_t)blockIdx.x * 16 + row) * 256;
  c32 v[16];
#pragma unroll
  for (int a = 0; a < 16; a++) v[a] = p[16*a + b];
  __syncthreads();
  fft256_core<INV>(v, b, tile + row*272, ltw);
#pragma unroll
  for (int d = 0; d < 16; d++) p[b + 16*d] = v[SLOT16(d)];
}

// ---------- inverse rfft along y (paired z-columns) + bias, writes out ----------
__global__ __launch_bounds__(256) void k_inv_y(const c32* __restrict__ r1, const float* __restrict__ bias,
                                               const float2* __restrict__ tw, float* __restrict__ out){
  __shared__ c32 tile[16*272];
  __shared__ float2 ltw[256];
  c32* SA = tile;
  int t = threadIdx.x;
  ltw[t] = tw[t];
  int bo = blockIdx.x >> 3;
  int z0 = (blockIdx.x & 7) << 5;
  for (int j = 0; j < 17; j++){
    int idx = t + 256*j;
    if (idx >= 129*32) break;
    int y = idx >> 5, zi = idx & 31;
    SA[y*33 + zi] = r1[((size_t)bo * 129 + y) * 256 + z0 + zi];
  }
  __syncthreads();
  int p = t >> 4, b = t & 15;
  c32 v[16];
#pragma unroll
  for (int a = 0; a < 16; a++){
    int k = 16*a + b;
    int m = (k <= 128) ? k : 256 - k;
    c32 A = SA[m*33 + 2*p], B = SA[m*33 + 2*p + 1];
    if (k == 0 || k == 128)  v[a] = make_float2(A.x, B.x);
    else if (k < 128)        v[a] = make_float2(A.x - B.y, A.y + B.x);
    else                     v[a] = make_float2(A.x + B.y, B.x - A.y);
  }
  __syncthreads();
  fft256_core<1>(v, b, tile + p*272, ltw);
  float bv = bias[bo & 31];
  float* o0 = out + ((size_t)bo * 256 + z0 + 2*p) * 256;
#pragma unroll
  for (int d = 0; d < 16; d++){
    c32 zz = v[SLOT16(d)];
    o0[b + 16*d]       = zz.x + bv;
    o0[256 + b + 16*d] = zz.y + bv;
  }
}

// ---------- mode mixing r1: y4-tile, x-pair float4 loads, y-half-split R2 in LDS ----------
// 256 threads = 128 x-pairs * 2 y-halves. grid 1056 = 8 XCD chunks * 132 (y-major).
__global__ __launch_bounds__(256, 4) void k_r1(const c32* __restrict__ alpha,
                                               const float* __restrict__ rr, const float* __restrict__ ri,
                                               const float* __restrict__ p1r, const float* __restrict__ p1i,
                                               const c32* __restrict__ P2,
                                               c32* __restrict__ r1){
  __shared__ float4 R2h[2][512];   // [yhalf][i*16+k] = (r@yA, r@yB, i@yA, i@yB), 16KB
  int t = threadIdx.x;
  int j = blockIdx.x;
  int g = (j & 7) * 132 + (j >> 3);          // XCD-chunked
  int y4 = g >> 5, o = g & 31;               // y4: 0..32
  int y0 = y4 * 4;
  // build R2 for 4 y's, pre-split by y-half
#pragma unroll
  for (int e = 0; e < 2; e++){
    int flat = t + e * 256;                  // i*16 + k
    int i = flat >> 4, k = flat & 15;
    int io = i * 32 + o;
    int iok = io * 16 + k;
    float ar[4] = {0.f,0.f,0.f,0.f}, ai[4] = {0.f,0.f,0.f,0.f};
#pragma unroll
    for (int l = 0; l < 9; l++){
      float rsr = rr[iok*9 + l], rsi = ri[iok*9 + l];
#pragma unroll
      for (int yy = 0; yy < 4; yy++){
        int ya = y0 + yy; if (ya > 128) ya = 128;
        c32 p2 = P2[((size_t)io * NYF + ya) * 10 + l];
        ar[yy] = fmaf(rsr, p2.x, ar[yy]); ar[yy] = fmaf(-rsi, p2.y, ar[yy]);
        ai[yy] = fmaf(rsr, p2.y, ai[yy]); ai[yy] = fmaf( rsi, p2.x, ai[yy]);
      }
    }
    R2h[0][flat] = make_float4(ar[0], ar[1], ai[0], ai[1]);
    R2h[1][flat] = make_float4(ar[2], ar[3], ai[2], ai[3]);
  }
  __syncthreads();
  int xp = t & 127, yh = t >> 7;
  int x0 = 2 * xp;
  int yA = y0 + 2 * yh;                      // thread's y pair: yA, yA+1
  int yAc = (yA     > 128) ? 128 : yA;
  int yBc = (yA + 1 > 128) ? 128 : yA + 1;
  bool wA = (yA     <= 128);
  bool wB = (yA + 1 <= 128);
  float fx0 = (x0     < 128) ? (float)x0       : (float)(x0 - 256);
  float fx1 = (x0 + 1 < 128) ? (float)(x0 + 1) : (float)(x0 + 1 - 256);
  float lam0 = 6.2831853071795864f * fx0;
  float lam1 = 6.2831853071795864f * fx1;
  const float4* __restrict__ R2u = R2h[yh];  // wave-uniform base
  float acr[8][2][2], aci[8][2][2];          // [b][y 0/1][x 0/1]
#pragma unroll
  for (int b = 0; b < 8; b++)
#pragma unroll
    for (int yy = 0; yy < 2; yy++){
      acr[b][yy][0] = 0.f; acr[b][yy][1] = 0.f;
      aci[b][yy][0] = 0.f; aci[b][yy][1] = 0.f;
    }
  size_t yoffA = (size_t)yAc * 256, yoffB = (size_t)yBc * 256;
  for (int i = 0; i < 32; i++){
    int io = i * 32 + o;
    const float* pr = p1r + io * 16;
    const float* pim = p1i + io * 16;
    float hwr[2][2] = {{0.f,0.f},{0.f,0.f}};  // [y][x]
    float hwi[2][2] = {{0.f,0.f},{0.f,0.f}};
#pragma unroll
    for (int k = 0; k < 16; k++){
      float a = -pr[k];
      float b0 = lam0 - pim[k];
      float b1 = lam1 - pim[k];
      float inv0 = frcp(fmaf(a, a, b0 * b0));
      float inv1 = frcp(fmaf(a, a, b1 * b1));
      float px0 = a * inv0, py0 = -b0 * inv0;
      float px1 = a * inv1, py1 = -b1 * inv1;
      float4 q = R2u[i*16 + k];               // (rA, rB, iA, iB)
      hwr[0][0] = fmaf(px0, q.x, hwr[0][0]); hwr[0][0] = fmaf(-py0, q.z, hwr[0][0]);
      hwi[0][0] = fmaf(px0, q.z, hwi[0][0]); hwi[0][0] = fmaf( py0, q.x, hwi[0][0]);
      hwr[0][1] = fmaf(px1, q.x, hwr[0][1]); hwr[0][1] = fmaf(-py1, q.z, hwr[0][1]);
      hwi[0][1] = fmaf(px1, q.z, hwi[0][1]); hwi[0][1] = fmaf( py1, q.x, hwi[0][1]);
      hwr[1][0] = fmaf(px0, q.y, hwr[1][0]); hwr[1][0] = fmaf(-py0, q.w, hwr[1][0]);
      hwi[1][0] = fmaf(px0, q.w, hwi[1][0]); hwi[1][0] = fmaf( py0, q.y, hwi[1][0]);
      hwr[1][1] = fmaf(px1, q.y, hwr[1][1]); hwr[1][1] = fmaf(-py1, q.w, hwr[1][1]);
      hwi[1][1] = fmaf(px1, q.w, hwi[1][1]); hwi[1][1] = fmaf( py1, q.y, hwi[1][1]);
    }
    const c32* ab = alpha + (size_t)i * 129 * 256 + x0;
#pragma unroll
    for (int b = 0; b < 8; b++){
      const c32* ap = ab + (size_t)b * 32 * 129 * 256;
      float4 vA = *(const float4*)(ap + yoffA);   // (re@x0, im@x0, re@x1, im@x1)
      float4 vB = *(const float4*)(ap + yoffB);
      acr[b][0][0]=fmaf(vA.x,hwr[0][0],acr[b][0][0]); acr[b][0][0]=fmaf(-vA.y,hwi[0][0],acr[b][0][0]);
      aci[b][0][0]=fmaf(vA.x,hwi[0][0],aci[b][0][0]); aci[b][0][0]=fmaf( vA.y,hwr[0][0],aci[b][0][0]);
      acr[b][0][1]=fmaf(vA.z,hwr[0][1],acr[b][0][1]); acr[b][0][1]=fmaf(-vA.w,hwi[0][1],acr[b][0][1]);
      aci[b][0][1]=fmaf(vA.z,hwi[0][1],aci[b][0][1]); aci[b][0][1]=fmaf( vA.w,hwr[0][1],aci[b][0][1]);
      acr[b][1][0]=fmaf(vB.x,hwr[1][0],acr[b][1][0]); acr[b][1][0]=fmaf(-vB.y,hwi[1][0],acr[b][1][0]);
      aci[b][1][0]=fmaf(vB.x,hwi[1][0],aci[b][1][0]); aci[b][1][0]=fmaf( vB.y,hwr[1][0],aci[b][1][0]);
      acr[b][1][1]=fmaf(vB.z,hwr[1][1],acr[b][1][1]); acr[b][1][1]=fmaf(-vB.w,hwi[1][1],acr[b][1][1]);
      aci[b][1][1]=fmaf(vB.z,hwi[1][1],aci[b][1][1]); aci[b][1][1]=fmaf( vB.w,hwr[1][1],aci[b][1][1]);
    }
  }
#pragma unroll
  for (int b = 0; b < 8; b++){
    if (wA){
      float4 st = make_float4(acr[b][0][0], aci[b][0][0], acr[b][0][1], aci[b][0][1]);
      *(float4*)(r1 + (((size_t)(b*32 + o) * 129) + yA) * 256 + x0) = st;
    }
    if (wB){
      float4 st = make_float4(acr[b][1][0], aci[b][1][0], acr[b][1][1], aci[b][1][1]);
      *(float4*)(r1 + (((size_t)(b*32 + o) * 129) + yA + 1) * 256 + x0) = st;
    }
  }
}

// ---------- r2[b,io,k,l]: phase1 scalar-P2 + 4-deep prefetch (r14 form), phase2 stride-11 Ts ----------
// Ts rows: 11 c32 = 88B = 22 banks; gcd(22,32)=2 -> read-conflict-free; LDS 22528B -> 7 blocks/CU.
__global__ __launch_bounds__(256) void k_r2k(const c32* __restrict__ alpha,
                                             const float* __restrict__ p1r, const float* __restrict__ p1i,
                                             const c32* __restrict__ P2,
                                             const float* __restrict__ rr, const float* __restrict__ ri,
                                             c32* __restrict__ r2){
  __shared__ c32 Ts[256 * 11];
  int t = threadIdx.x;
  int j = blockIdx.x;               // 8192 = 8 XCD * 1024
  int bid = (j & 7) * 1024 + (j >> 3);  // same-bi (32 o's) consecutive per XCD
  int o = bid & 31; int bi = bid >> 5;
  int i = bi & 31;  int b = bi >> 5;
  int io = i * COut + o;
  { // phase 1: T[l][x=t] = sum_y alpha[bi,y,t] * P2row[y][l]; P2 reads are wave-uniform -> s_load
    float tr[9], ti[9];
#pragma unroll
    for (int l = 0; l < 9; l++){ tr[l] = 0.f; ti[l] = 0.f; }
    const c32* ap = alpha + (size_t)bi * NYF * 256 + t;
    const float* __restrict__ P2u = (const float*)(P2 + (size_t)io * NYF * 10);
    c32 a0 = ap[0], a1 = ap[256], a2 = ap[512], a3 = ap[768];
#define R2K_BODY(aa, Y, PF) { \
      const float* prw = P2u + (size_t)(Y) * 20; \
      float axr = (aa).x, ayi = (aa).y; \
      PF; \
      _Pragma("unroll") \
      for (int l = 0; l < 9; l++){ \
        float pc = prw[2*l], ps = prw[2*l+1]; \
        tr[l] = fmaf(axr, pc, tr[l]); tr[l] = fmaf(-ayi, ps, tr[l]); \
        ti[l] = fmaf(axr, ps, ti[l]); ti[l] = fmaf(ayi, pc, ti[l]); } }
    for (int yb = 0; yb < 128; yb += 4){
      R2K_BODY(a0, yb+0, a0 = ap[(size_t)(yb+4)*256]);
      R2K_BODY(a1, yb+1, a1 = ap[(size_t)(yb+5)*256]);
      R2K_BODY(a2, yb+2, a2 = ap[(size_t)(yb+6)*256]);
      R2K_BODY(a3, yb+3, a3 = ap[(size_t)(yb+7)*256]);
    }
    R2K_BODY(a0, 128, );
#undef R2K_BODY
    c32* myrow = Ts + t * 11;
#pragma unroll
    for (int l = 0; l < 9; l++) myrow[l] = make_float2(tr[l], ti[l]);
  }
  __syncthreads();
  { // phase 2: r2[k,l] = -res[k,l] * sum_x P1[k,x]*T[l,x]; stride-11 rows -> conflict-free b64 reads
    int k = t >> 4, c = t & 15;
    float pa = -p1r[io*16 + k];
    float pb =  p1i[io*16 + k];
    float gr[9], gi[9];
#pragma unroll
    for (int l = 0; l < 9; l++){ gr[l] = 0.f; gi[l] = 0.f; }
#pragma unroll 4
    for (int jj = 0; jj < 16; jj++){
      int xx = c + 16*jj;
      float fx = (xx < 128) ? (float)xx : (float)(xx - 256);
      float bb = 6.2831853071795864f * fx - pb;
      float inv = frcp(fmaf(pa, pa, bb * bb));
      float px = pa * inv, py = -bb * inv;
      const c32* trow = Ts + xx * 11;
      float Trv[9], Tiv[9];
#pragma unroll
      for (int l = 0; l < 9; l++){
        c32 q = trow[l];
        Trv[l] = q.x; Tiv[l] = q.y;
      }
#pragma unroll
      for (int l = 0; l < 9; l++){
        gr[l] = fmaf(px, Trv[l], gr[l]); gr[l] = fmaf(-py, Tiv[l], gr[l]);
        gi[l] = fmaf(px, Tiv[l], gi[l]); gi[l] = fmaf( py, Trv[l], gi[l]);
      }
    }
#pragma unroll
    for (int s = 1; s < 16; s <<= 1){
#pragma unroll
      for (int l = 0; l < 9; l++){
        gr[l] += __shfl_xor(gr[l], s, 64);
        gi[l] += __shfl_xor(gi[l], s, 64);
      }
    }
    if (c == 0){
#pragma unroll
      for (int l = 0; l < 9; l++){
        float resr = rr[(io*16 + k)*9 + l];
        float resi = ri[(io*16 + k)*9 + l];
        r2[((size_t)b * NIO + io) * NKL + k*9 + l] =
          make_float2(-(resr*gr[l] - resi*gi[l]), -(resr*gi[l] + resi*gr[l]));
      }
    }
  }
}

// ---------- x2 path: split-bf16 MFMA GEMM pipeline ----------
__global__ __launch_bounds__(256) void k_e2b(const float* __restrict__ p2r, const float* __restrict__ p2i,
                                             unsigned int* __restrict__ B){
  int j = blockIdx.x;
  int o = j & 31, ic = j >> 5;
  int w = threadIdx.x;
  float tt = (float)w * (1.0f / 256.0f);
  unsigned int* brow = B + ((size_t)o * 256 + w) * 576;   // 576 uints = 1152 halves
#pragma unroll
  for (int ii = 0; ii < 4; ii++){
    int i = ic * 4 + ii;
    int io = i * 32 + o;
#pragma unroll
    for (int l = 0; l < 9; l++){
      float pr = p2r[io*9 + l], pi = p2i[io*9 + l];
      float er = expf(pr * tt);
      float s, c; sincosf(pi * tt, &s, &c);
      float vr = er * c, vi = -er * s;
      unsigned short rh, rl, ih, il;
      split_bf(vr, rh, rl); split_bf(vi, ih, il);
      brow[i*9 + l]       = (unsigned int)rh | ((unsigned int)ih << 16);
      brow[288 + i*9 + l] = (unsigned int)rl | ((unsigned int)il << 16);
    }
  }
}

__global__ __launch_bounds__(256) void k_v(const c32* __restrict__ r2, const c32* __restrict__ E1,
                                           unsigned int* __restrict__ Ahi, unsigned int* __restrict__ Alo){
  int t = threadIdx.x;                 // z
  int j = blockIdx.x;                  // 1024
  int o = j & 31;
  int rest = j >> 5;                   // 0..31
  int b = rest & 7, ic = rest >> 3;    // ic 0..3
  size_t rowoff = ((size_t)o * 2048 + b * 256 + t) * 288;
  unsigned int* AH = Ahi + rowoff;
  unsigned int* AL = Alo + rowoff;
#pragma unroll 1
  for (int ii = 0; ii < 8; ii++){
    int i = ic * 8 + ii;
    int io = i * 32 + o;
    const c32* e1p = E1 + (size_t)io * 16 * 256 + t;
    c32 e[16];
#pragma unroll
    for (int k = 0; k < 16; k++) e[k] = e1p[(size_t)k * 256];
    const c32* rp = r2 + ((size_t)b * NIO + io) * NKL;
#pragma unroll
    for (int l = 0; l < 9; l++){
      c32 acc = make_float2(0.0f, 0.0f);
#pragma unroll
      for (int k = 0; k < 16; k++) acc = cfma(rp[k*9 + l], e[k], acc);
      unsigned short rh, rl, ih, il;
      split_bf(acc.x, rh, rl); split_bf(acc.y, ih, il);
      AH[i*9 + l] = (unsigned int)rh | ((unsigned int)ih << 16);
      AL[i*9 + l] = (unsigned int)rl | ((unsigned int)il << 16);
    }
  }
}

// GEMM: per o: C[2048][256] += Re(A*B^T), split-bf16 3-product schedule, 54 K-chunks of 32.
#define ALO_H 37748736u
__global__ __launch_bounds__(256) void k_x2m(const unsigned short* __restrict__ A,
                                             const unsigned short* __restrict__ B,
                                             float* __restrict__ out){
  __shared__ __align__(16) unsigned short At[128*32];
  __shared__ __align__(16) unsigned short Bt[128*32];
  int t = threadIdx.x;
  int j = blockIdx.x;                   // 1024
  int orig = (j & 7) * 128 + (j >> 3);  // same-o blocks grouped per XCD
  int o  = orig >> 5;
  int mb = (orig >> 1) & 15;
  int nb = orig & 1;
  const unsigned short* Ab = A + ((size_t)o*2048 + mb*128 + (t>>2))*576 + (t&3)*8;
  const unsigned short* Bb = B + ((size_t)o*256  + nb*128 + (t>>2))*1152 + (t&3)*8;
  int ln = t & 63;
  int wm = t >> 7, wn = (t >> 6) & 1;
  int lrow = ln & 15, lk = (ln >> 4) * 8;
  f32x4 acc[4][4];
#pragma unroll
  for (int mi = 0; mi < 4; mi++)
#pragma unroll
    for (int ni = 0; ni < 4; ni++) acc[mi][ni] = (f32x4){0.f,0.f,0.f,0.f};

  for (int ks = 0; ks < 54; ks++){
    int kA = ks % 18;
    int kB = ks % 36;
    const unsigned short* Ap = Ab + (ks >= 36 ? (size_t)ALO_H : 0) + (size_t)kA*32;
    __syncthreads();
    GLOAD16(At + (size_t)t*8,        Ap);
    GLOAD16(At + 2048 + (size_t)t*8, Ap + (size_t)64*576);
    GLOAD16(Bt + (size_t)t*8,        Bb + (size_t)kB*32);
    GLOAD16(Bt + 2048 + (size_t)t*8, Bb + (size_t)kB*32 + (size_t)64*1152);
    __syncthreads();
    bf16x8 av[4], bv[4];
#pragma unroll
    for (int mi = 0; mi < 4; mi++)
      av[mi] = *(const bf16x8*)(At + (wm*64 + mi*16 + lrow)*32 + lk);
#pragma unroll
    for (int ni = 0; ni < 4; ni++)
      bv[ni] = *(const bf16x8*)(Bt + (wn*64 + ni*16 + lrow)*32 + lk);
#pragma unroll
    for (int mi = 0; mi < 4; mi++)
#pragma unroll
      for (int ni = 0; ni < 4; ni++)
        acc[mi][ni] = __builtin_amdgcn_mfma_f32_16x16x32_bf16(av[mi], bv[ni], acc[mi][ni], 0, 0, 0);
  }
  int nglob = nb*128 + wn*64 + (ln & 15);
#pragma unroll
  for (int mi = 0; mi < 4; mi++){
#pragma unroll
    for (int r = 0; r < 4; r++){
      int m = mb*128 + wm*64 + mi*16 + (ln >> 4)*4 + r;
      int b = m >> 8, z = m & 255;
      float* op = out + (((size_t)(b*32 + o) * 256 + z) * 256) + nglob;
#pragma unroll
      for (int ni = 0; ni < 4; ni++)
        op[ni*16] += acc[mi][ni][r];
    }
  }
}

extern "C" void kernel_launch(void* const* d_in, const int* in_sizes, int n_in,
                              void* d_out, int out_size, void* d_ws, size_t ws_size,
                              hipStream_t stream){
  const float* x    = (const float*)d_in[0];
  const float* rr   = (const float*)d_in[1];
  const float* ri   = (const float*)d_in[2];
  const float* p1r  = (const float*)d_in[3];
  const float* p1i  = (const float*)d_in[4];
  const float* p2r  = (const float*)d_in[5];
  const float* p2i  = (const float*)d_in[6];
  const float* bias = (const float*)d_in[7];
  float* out = (float*)d_out;

  // ws layout (offsets unchanged; P2b in old R2b hole)
  char* ws = (char*)d_ws;
  size_t off = 0;
  c32* alpha = (c32*)(ws + off); off += (size_t)NB * CIn * NYF * NN1 * sizeof(c32);   // 67.6 MB
  c32* r1b   = (c32*)(ws + off); off += (size_t)NB * COut * NYF * NN1 * sizeof(c32);  // 67.6 MB
  off += (size_t)NIO * NK1 * NN1 * sizeof(c32);                                       // (hole)
  c32* P2b   = (c32*)(ws + off); off += (size_t)NIO * NYF * 10 * sizeof(c32);         // 10.6 MB
  off += (size_t)NIO * NK1 * NYF * sizeof(c32) - (size_t)NIO * NYF * 10 * sizeof(c32)
       + (size_t)NIO * NK2 * NYF * sizeof(c32);                                       // keep E1b offset identical
  c32* E1b   = (c32*)(ws + off); off += (size_t)NIO * NK1 * NN1 * sizeof(c32);        // 33.6 MB
  c32* r2b   = (c32*)(ws + off); off += (size_t)NB * NIO * NKL * sizeof(c32);         //  9.4 MB
  float2* tw = (float2*)(ws + off); off += 256 * sizeof(float2);
  unsigned short* Abf  = (unsigned short*)(ws + 0);
  unsigned short* E2bf = (unsigned short*)(ws + 150994944);

  k_tw<<<1, 256, 0, stream>>>(tw);
  k_p2<<<(NIO * NYF + 255) / 256, 256, 0, stream>>>(p2r, p2i, P2b);
  k_e1<<<NIO * NK1, 256, 0, stream>>>(p1r, p1i, E1b);

  k_fwd_y<<<NB * CIn * 8, 256, 0, stream>>>(x, tw, alpha);
  k_fft_x<0><<<NB * CIn * NYF / 16, 256, 0, stream>>>(tw, alpha);

  k_r1<<<1056, 256, 0, stream>>>(alpha, rr, ri, p1r, p1i, P2b, r1b);
  k_r2k<<<NB * CIn * COut, 256, 0, stream>>>(alpha, p1r, p1i, P2b, rr, ri, r2b);

  k_fft_x<1><<<NB * COut * NYF / 16, 256, 0, stream>>>(tw, r1b);
  k_inv_y<<<NB * COut * 8, 256, 0, stream>>>(r1b, bias, tw, out);

  k_e2b<<<256, 256, 0, stream>>>(p2r, p2i, (unsigned int*)E2bf);
  k_v<<<1024, 256, 0, stream>>>(r2b, E1b, (unsigned int*)Abf, (unsigned int*)(Abf + ALO_H));
  k_x2m<<<1024, 256, 0, stream>>>(Abf, E2bf, out);
}